// Round 5
// baseline (62.380 us; speedup 1.0000x reference)
//
#include <hip/hip_runtime.h>

// Problem constants (from the reference): CNO=10000, PAD=10001, KS=10003.
#define CNO_C 10000
#define PAD_C 10001
#define KS_C  10003

// Native vector type for nontemporal stores (__builtin_nontemporal_store
// rejects HIP's class-type int4).
typedef int iv4 __attribute__((ext_vector_type(4)));

// -------------------------------------------------------------------------
// mr==64 fast path (flat, massively parallel): one thread per (query, 8
// consecutive offsets). 8 threads/query, 1.6M threads. Per thread:
//   5 metadata loads (wave-broadcast) + 2 gather dwordx4 + 4 store dwordx4.
// Stores are nontemporal: output is write-once/never-re-read, keep L2 for
// the order[] gather tables (~24 MB, L2-resident).
// -------------------------------------------------------------------------
__global__ __launch_bounds__(256) void akfi_vec8(
    const int* __restrict__ qa,                                   // B x 3
    const int* __restrict__ o0, const int* __restrict__ s0, const int* __restrict__ l0,
    const int* __restrict__ o1, const int* __restrict__ s1, const int* __restrict__ l1,
    const int* __restrict__ op, const int* __restrict__ sp, const int* __restrict__ lp,
    int n0, int n1, int npred,
    int F, int B,
    int* __restrict__ out_idx,                                    // B x 64
    int* __restrict__ out_valid)                                  // B x 64 (0/1)
{
    long long t = (long long)blockIdx.x * blockDim.x + threadIdx.x;
    long long total = (long long)B * 8;
    if (t >= total) return;

    int q  = (int)(t >> 3);
    int j8 = (int)(t & 7) << 3;                // 0,8,...,56

    int p  = qa[q * 3 + 0];
    int a0 = qa[q * 3 + 1];
    int a1 = qa[q * 3 + 2];

    bool is_c0 = (a0 <= CNO_C) && (a0 != PAD_C);
    bool is_c1 = (a1 <= CNO_C) && (a1 != PAD_C);
    bool both  = (!is_c0) && (!is_c1) && (p != PAD_C);

    // Reference select order: is_c0 -> t0; elif both_var -> pred; else t1.
    const int* order; const int* starts; const int* lens;
    int key, nsz; bool isc;
    if (is_c0)      { order = o0; starts = s0; lens = l0; key = p * KS_C + a0; nsz = n0;    isc = true;  }
    else if (both)  { order = op; starts = sp; lens = lp; key = p;             nsz = npred; isc = true;  }
    else            { order = o1; starts = s1; lens = l1; key = p * KS_C + a1; nsz = n1;    isc = is_c1; }

    int safe = min(max(key, 0), nsz - 1);
    int left = starts[safe];
    int cnt  = min(lens[safe], 64);
    if (!isc) cnt = 0;                         // valid = (j < cnt) && isc
    const int Fm1 = F - 1;

    int idx0 = left + j8;                      // reference clamps each to [0, F-1]
    int f[8];
    if (idx0 >= 0 && idx0 + 7 <= Fm1) {
        // contiguous, in-bounds: 2x global_load_dwordx4
#pragma unroll
        for (int e = 0; e < 8; ++e) f[e] = order[idx0 + e];
    } else {
#pragma unroll
        for (int e = 0; e < 8; ++e) f[e] = order[min(max(idx0 + e, 0), Fm1)];
    }

    iv4 fv0 = (iv4){f[0], f[1], f[2], f[3]};
    iv4 fv1 = (iv4){f[4], f[5], f[6], f[7]};
    iv4 vv0 = (iv4){j8     < cnt ? 1 : 0, j8 + 1 < cnt ? 1 : 0,
                    j8 + 2 < cnt ? 1 : 0, j8 + 3 < cnt ? 1 : 0};
    iv4 vv1 = (iv4){j8 + 4 < cnt ? 1 : 0, j8 + 5 < cnt ? 1 : 0,
                    j8 + 6 < cnt ? 1 : 0, j8 + 7 < cnt ? 1 : 0};

    long long ob = ((long long)q << 6) + j8;   // 16B-aligned
    __builtin_nontemporal_store(fv0, reinterpret_cast<iv4*>(out_idx + ob));
    __builtin_nontemporal_store(fv1, reinterpret_cast<iv4*>(out_idx + ob + 4));
    __builtin_nontemporal_store(vv0, reinterpret_cast<iv4*>(out_valid + ob));
    __builtin_nontemporal_store(vv1, reinterpret_cast<iv4*>(out_valid + ob + 4));
}

// -------------------------------------------------------------------------
// Generic fallbacks (mr != 64).
// -------------------------------------------------------------------------
__global__ __launch_bounds__(256) void akfi_vec4(
    const int* __restrict__ qa,
    const int* __restrict__ o0, const int* __restrict__ s0, const int* __restrict__ l0,
    const int* __restrict__ o1, const int* __restrict__ s1, const int* __restrict__ l1,
    const int* __restrict__ op, const int* __restrict__ sp, const int* __restrict__ lp,
    int n0, int n1, int npred,
    int F, int B, int mr,
    int* __restrict__ out_idx,
    int* __restrict__ out_valid)
{
    long long t = (long long)blockIdx.x * blockDim.x + threadIdx.x;
    int per_q = mr >> 2;
    long long total = (long long)B * per_q;
    if (t >= total) return;

    int q = (int)(t / per_q), j4 = (int)(t % per_q) << 2;

    int p  = qa[q * 3 + 0];
    int a0 = qa[q * 3 + 1];
    int a1 = qa[q * 3 + 2];
    bool is_c0 = (a0 <= CNO_C) && (a0 != PAD_C);
    bool is_c1 = (a1 <= CNO_C) && (a1 != PAD_C);
    bool both  = (!is_c0) && (!is_c1) && (p != PAD_C);

    const int* order; const int* starts; const int* lens;
    int key, nsz; bool isc;
    if (is_c0)      { order = o0; starts = s0; lens = l0; key = p * KS_C + a0; nsz = n0;    isc = true;  }
    else if (both)  { order = op; starts = sp; lens = lp; key = p;             nsz = npred; isc = true;  }
    else            { order = o1; starts = s1; lens = l1; key = p * KS_C + a1; nsz = n1;    isc = is_c1; }

    int safe = min(max(key, 0), nsz - 1);
    int left = starts[safe];
    int cnt  = min(lens[safe], mr);
    if (!isc) cnt = 0;
    int Fm1 = F - 1;

    int idx0 = left + j4;
    int f0, f1, f2, f3;
    if (idx0 >= 0 && idx0 + 3 <= Fm1) {
        f0 = order[idx0]; f1 = order[idx0 + 1]; f2 = order[idx0 + 2]; f3 = order[idx0 + 3];
    } else {
        f0 = order[min(max(idx0,     0), Fm1)];
        f1 = order[min(max(idx0 + 1, 0), Fm1)];
        f2 = order[min(max(idx0 + 2, 0), Fm1)];
        f3 = order[min(max(idx0 + 3, 0), Fm1)];
    }

    iv4 fv = (iv4){f0, f1, f2, f3};
    iv4 vv = (iv4){j4 < cnt ? 1 : 0, j4 + 1 < cnt ? 1 : 0,
                   j4 + 2 < cnt ? 1 : 0, j4 + 3 < cnt ? 1 : 0};
    long long ob = (long long)q * mr + j4;
    *reinterpret_cast<iv4*>(out_idx + ob)   = fv;
    *reinterpret_cast<iv4*>(out_valid + ob) = vv;
}

__global__ __launch_bounds__(256) void akfi_scalar(
    const int* __restrict__ qa,
    const int* __restrict__ o0, const int* __restrict__ s0, const int* __restrict__ l0,
    const int* __restrict__ o1, const int* __restrict__ s1, const int* __restrict__ l1,
    const int* __restrict__ op, const int* __restrict__ sp, const int* __restrict__ lp,
    int n0, int n1, int npred,
    int F, int B, int mr,
    int* __restrict__ out_idx,
    int* __restrict__ out_valid)
{
    long long t = (long long)blockIdx.x * blockDim.x + threadIdx.x;
    long long total = (long long)B * (long long)mr;
    if (t >= total) return;
    int q = (int)(t / mr), j = (int)(t % mr);

    int p  = qa[q * 3 + 0];
    int a0 = qa[q * 3 + 1];
    int a1 = qa[q * 3 + 2];
    bool is_c0 = (a0 <= CNO_C) && (a0 != PAD_C);
    bool is_c1 = (a1 <= CNO_C) && (a1 != PAD_C);
    bool both  = (!is_c0) && (!is_c1) && (p != PAD_C);

    const int* order; const int* starts; const int* lens;
    int key, nsz; bool isc;
    if (is_c0)      { order = o0; starts = s0; lens = l0; key = p * KS_C + a0; nsz = n0;    isc = true;  }
    else if (both)  { order = op; starts = sp; lens = lp; key = p;             nsz = npred; isc = true;  }
    else            { order = o1; starts = s1; lens = l1; key = p * KS_C + a1; nsz = n1;    isc = is_c1; }

    int safe = min(max(key, 0), nsz - 1);
    int left = starts[safe];
    int cnt  = min(lens[safe], mr);
    int idx  = min(max(left + j, 0), F - 1);

    long long ob = (long long)q * mr + j;
    out_idx[ob]   = order[idx];
    out_valid[ob] = (isc && j < cnt) ? 1 : 0;
}

extern "C" void kernel_launch(void* const* d_in, const int* in_sizes, int n_in,
                              void* d_out, int out_size, void* d_ws, size_t ws_size,
                              hipStream_t stream) {
    const int* qa = (const int*)d_in[0];
    const int* o0 = (const int*)d_in[1];
    const int* s0 = (const int*)d_in[2];
    const int* l0 = (const int*)d_in[3];
    const int* o1 = (const int*)d_in[4];
    const int* s1 = (const int*)d_in[5];
    const int* l1 = (const int*)d_in[6];
    const int* op = (const int*)d_in[7];
    const int* sp = (const int*)d_in[8];
    const int* lp = (const int*)d_in[9];
    int B  = in_sizes[0] / 3;
    int F  = in_sizes[1];
    int n0 = in_sizes[2];
    int n1 = in_sizes[5];
    int npred = in_sizes[8];
    int mr = out_size / (2 * B);

    int* out_idx   = (int*)d_out;
    int* out_valid = (int*)d_out + (long long)B * mr;

    int block = 256;
    if (mr == 64) {
        long long total = (long long)B * 8;
        int blocks = (int)((total + block - 1) / block);
        akfi_vec8<<<blocks, block, 0, stream>>>(
            qa, o0, s0, l0, o1, s1, l1, op, sp, lp,
            n0, n1, npred, F, B, out_idx, out_valid);
    } else if ((mr & 3) == 0) {
        long long total = (long long)B * (mr >> 2);
        int blocks = (int)((total + block - 1) / block);
        akfi_vec4<<<blocks, block, 0, stream>>>(
            qa, o0, s0, l0, o1, s1, l1, op, sp, lp,
            n0, n1, npred, F, B, mr, out_idx, out_valid);
    } else {
        long long total = (long long)B * (long long)mr;
        int blocks = (int)((total + block - 1) / block);
        akfi_scalar<<<blocks, block, 0, stream>>>(
            qa, o0, s0, l0, o1, s1, l1, op, sp, lp,
            n0, n1, npred, F, B, mr, out_idx, out_valid);
    }
}

// Round 6
// 33.396 us; speedup vs baseline: 1.8679x; 1.8679x over previous
//
#include <hip/hip_runtime.h>

// Problem constants (from the reference): CNO=10000, PAD=10001, KS=10003.
#define CNO_C 10000
#define PAD_C 10001
#define KS_C  10003

typedef int iv4 __attribute__((ext_vector_type(4)));

// -------------------------------------------------------------------------
// mr==64 fast path (flat, massively parallel): one thread per (query, 8
// consecutive offsets). 8 threads/query, 1.6M threads. Per thread:
//   5 metadata loads (wave-broadcast) + 2 gather dwordx4 + 4 store dwordx4.
// Plain cached stores: contiguous streams write-combine into full 64B lines
// in L2 (R5 lesson: nontemporal stores caused 1.85x write amplification).
// -------------------------------------------------------------------------
__global__ __launch_bounds__(256) void akfi_vec8(
    const int* __restrict__ qa,                                   // B x 3
    const int* __restrict__ o0, const int* __restrict__ s0, const int* __restrict__ l0,
    const int* __restrict__ o1, const int* __restrict__ s1, const int* __restrict__ l1,
    const int* __restrict__ op, const int* __restrict__ sp, const int* __restrict__ lp,
    int n0, int n1, int npred,
    int F, int B,
    int* __restrict__ out_idx,                                    // B x 64
    int* __restrict__ out_valid)                                  // B x 64 (0/1)
{
    long long t = (long long)blockIdx.x * blockDim.x + threadIdx.x;
    long long total = (long long)B * 8;
    if (t >= total) return;

    int q  = (int)(t >> 3);
    int j8 = (int)(t & 7) << 3;                // 0,8,...,56

    int p  = qa[q * 3 + 0];
    int a0 = qa[q * 3 + 1];
    int a1 = qa[q * 3 + 2];

    bool is_c0 = (a0 <= CNO_C) && (a0 != PAD_C);
    bool is_c1 = (a1 <= CNO_C) && (a1 != PAD_C);
    bool both  = (!is_c0) && (!is_c1) && (p != PAD_C);

    // Reference select order: is_c0 -> t0; elif both_var -> pred; else t1.
    const int* order; const int* starts; const int* lens;
    int key, nsz; bool isc;
    if (is_c0)      { order = o0; starts = s0; lens = l0; key = p * KS_C + a0; nsz = n0;    isc = true;  }
    else if (both)  { order = op; starts = sp; lens = lp; key = p;             nsz = npred; isc = true;  }
    else            { order = o1; starts = s1; lens = l1; key = p * KS_C + a1; nsz = n1;    isc = is_c1; }

    int safe = min(max(key, 0), nsz - 1);
    int left = starts[safe];
    int cnt  = min(lens[safe], 64);
    if (!isc) cnt = 0;                         // valid = (j < cnt) && isc
    const int Fm1 = F - 1;

    int idx0 = left + j8;                      // reference clamps each to [0, F-1]
    int f[8];
    if (idx0 >= 0 && idx0 + 7 <= Fm1) {
        // contiguous, in-bounds: 2x global_load_dwordx4
#pragma unroll
        for (int e = 0; e < 8; ++e) f[e] = order[idx0 + e];
    } else {
#pragma unroll
        for (int e = 0; e < 8; ++e) f[e] = order[min(max(idx0 + e, 0), Fm1)];
    }

    iv4 fv0 = (iv4){f[0], f[1], f[2], f[3]};
    iv4 fv1 = (iv4){f[4], f[5], f[6], f[7]};
    iv4 vv0 = (iv4){j8     < cnt ? 1 : 0, j8 + 1 < cnt ? 1 : 0,
                    j8 + 2 < cnt ? 1 : 0, j8 + 3 < cnt ? 1 : 0};
    iv4 vv1 = (iv4){j8 + 4 < cnt ? 1 : 0, j8 + 5 < cnt ? 1 : 0,
                    j8 + 6 < cnt ? 1 : 0, j8 + 7 < cnt ? 1 : 0};

    long long ob = ((long long)q << 6) + j8;   // 16B-aligned
    *reinterpret_cast<iv4*>(out_idx + ob)       = fv0;
    *reinterpret_cast<iv4*>(out_idx + ob + 4)   = fv1;
    *reinterpret_cast<iv4*>(out_valid + ob)     = vv0;
    *reinterpret_cast<iv4*>(out_valid + ob + 4) = vv1;
}

// -------------------------------------------------------------------------
// Generic fallbacks (mr != 64).
// -------------------------------------------------------------------------
__global__ __launch_bounds__(256) void akfi_vec4(
    const int* __restrict__ qa,
    const int* __restrict__ o0, const int* __restrict__ s0, const int* __restrict__ l0,
    const int* __restrict__ o1, const int* __restrict__ s1, const int* __restrict__ l1,
    const int* __restrict__ op, const int* __restrict__ sp, const int* __restrict__ lp,
    int n0, int n1, int npred,
    int F, int B, int mr,
    int* __restrict__ out_idx,
    int* __restrict__ out_valid)
{
    long long t = (long long)blockIdx.x * blockDim.x + threadIdx.x;
    int per_q = mr >> 2;
    long long total = (long long)B * per_q;
    if (t >= total) return;

    int q = (int)(t / per_q), j4 = (int)(t % per_q) << 2;

    int p  = qa[q * 3 + 0];
    int a0 = qa[q * 3 + 1];
    int a1 = qa[q * 3 + 2];
    bool is_c0 = (a0 <= CNO_C) && (a0 != PAD_C);
    bool is_c1 = (a1 <= CNO_C) && (a1 != PAD_C);
    bool both  = (!is_c0) && (!is_c1) && (p != PAD_C);

    const int* order; const int* starts; const int* lens;
    int key, nsz; bool isc;
    if (is_c0)      { order = o0; starts = s0; lens = l0; key = p * KS_C + a0; nsz = n0;    isc = true;  }
    else if (both)  { order = op; starts = sp; lens = lp; key = p;             nsz = npred; isc = true;  }
    else            { order = o1; starts = s1; lens = l1; key = p * KS_C + a1; nsz = n1;    isc = is_c1; }

    int safe = min(max(key, 0), nsz - 1);
    int left = starts[safe];
    int cnt  = min(lens[safe], mr);
    if (!isc) cnt = 0;
    int Fm1 = F - 1;

    int idx0 = left + j4;
    int f0, f1, f2, f3;
    if (idx0 >= 0 && idx0 + 3 <= Fm1) {
        f0 = order[idx0]; f1 = order[idx0 + 1]; f2 = order[idx0 + 2]; f3 = order[idx0 + 3];
    } else {
        f0 = order[min(max(idx0,     0), Fm1)];
        f1 = order[min(max(idx0 + 1, 0), Fm1)];
        f2 = order[min(max(idx0 + 2, 0), Fm1)];
        f3 = order[min(max(idx0 + 3, 0), Fm1)];
    }

    iv4 fv = (iv4){f0, f1, f2, f3};
    iv4 vv = (iv4){j4 < cnt ? 1 : 0, j4 + 1 < cnt ? 1 : 0,
                   j4 + 2 < cnt ? 1 : 0, j4 + 3 < cnt ? 1 : 0};
    long long ob = (long long)q * mr + j4;
    *reinterpret_cast<iv4*>(out_idx + ob)   = fv;
    *reinterpret_cast<iv4*>(out_valid + ob) = vv;
}

__global__ __launch_bounds__(256) void akfi_scalar(
    const int* __restrict__ qa,
    const int* __restrict__ o0, const int* __restrict__ s0, const int* __restrict__ l0,
    const int* __restrict__ o1, const int* __restrict__ s1, const int* __restrict__ l1,
    const int* __restrict__ op, const int* __restrict__ sp, const int* __restrict__ lp,
    int n0, int n1, int npred,
    int F, int B, int mr,
    int* __restrict__ out_idx,
    int* __restrict__ out_valid)
{
    long long t = (long long)blockIdx.x * blockDim.x + threadIdx.x;
    long long total = (long long)B * (long long)mr;
    if (t >= total) return;
    int q = (int)(t / mr), j = (int)(t % mr);

    int p  = qa[q * 3 + 0];
    int a0 = qa[q * 3 + 1];
    int a1 = qa[q * 3 + 2];
    bool is_c0 = (a0 <= CNO_C) && (a0 != PAD_C);
    bool is_c1 = (a1 <= CNO_C) && (a1 != PAD_C);
    bool both  = (!is_c0) && (!is_c1) && (p != PAD_C);

    const int* order; const int* starts; const int* lens;
    int key, nsz; bool isc;
    if (is_c0)      { order = o0; starts = s0; lens = l0; key = p * KS_C + a0; nsz = n0;    isc = true;  }
    else if (both)  { order = op; starts = sp; lens = lp; key = p;             nsz = npred; isc = true;  }
    else            { order = o1; starts = s1; lens = l1; key = p * KS_C + a1; nsz = n1;    isc = is_c1; }

    int safe = min(max(key, 0), nsz - 1);
    int left = starts[safe];
    int cnt  = min(lens[safe], mr);
    int idx  = min(max(left + j, 0), F - 1);

    long long ob = (long long)q * mr + j;
    out_idx[ob]   = order[idx];
    out_valid[ob] = (isc && j < cnt) ? 1 : 0;
}

extern "C" void kernel_launch(void* const* d_in, const int* in_sizes, int n_in,
                              void* d_out, int out_size, void* d_ws, size_t ws_size,
                              hipStream_t stream) {
    const int* qa = (const int*)d_in[0];
    const int* o0 = (const int*)d_in[1];
    const int* s0 = (const int*)d_in[2];
    const int* l0 = (const int*)d_in[3];
    const int* o1 = (const int*)d_in[4];
    const int* s1 = (const int*)d_in[5];
    const int* l1 = (const int*)d_in[6];
    const int* op = (const int*)d_in[7];
    const int* sp = (const int*)d_in[8];
    const int* lp = (const int*)d_in[9];
    int B  = in_sizes[0] / 3;
    int F  = in_sizes[1];
    int n0 = in_sizes[2];
    int n1 = in_sizes[5];
    int npred = in_sizes[8];
    int mr = out_size / (2 * B);

    int* out_idx   = (int*)d_out;
    int* out_valid = (int*)d_out + (long long)B * mr;

    int block = 256;
    if (mr == 64) {
        long long total = (long long)B * 8;
        int blocks = (int)((total + block - 1) / block);
        akfi_vec8<<<blocks, block, 0, stream>>>(
            qa, o0, s0, l0, o1, s1, l1, op, sp, lp,
            n0, n1, npred, F, B, out_idx, out_valid);
    } else if ((mr & 3) == 0) {
        long long total = (long long)B * (mr >> 2);
        int blocks = (int)((total + block - 1) / block);
        akfi_vec4<<<blocks, block, 0, stream>>>(
            qa, o0, s0, l0, o1, s1, l1, op, sp, lp,
            n0, n1, npred, F, B, mr, out_idx, out_valid);
    } else {
        long long total = (long long)B * (long long)mr;
        int blocks = (int)((total + block - 1) / block);
        akfi_scalar<<<blocks, block, 0, stream>>>(
            qa, o0, s0, l0, o1, s1, l1, op, sp, lp,
            n0, n1, npred, F, B, mr, out_idx, out_valid);
    }
}

// Round 7
// 32.003 us; speedup vs baseline: 1.9492x; 1.0435x over previous
//
#include <hip/hip_runtime.h>

// Problem constants (from the reference): CNO=10000, PAD=10001, KS=10003.
#define CNO_C 10000
#define PAD_C 10001
#define KS_C  10003

typedef int iv4 __attribute__((ext_vector_type(4)));

// -------------------------------------------------------------------------
// mr==64 fast path: dual-query vec4. Thread t handles query pair
// (2u, 2u+1), u = t>>4, at chunk j4 = (t&15)*4. Two INDEPENDENT
// metadata->gather chains per thread (2x memory-level parallelism vs vec4)
// while keeping vec4's store pattern: 16 consecutive lanes x 16B = 256B
// fully-covered lines per store instruction (vec8's striped stores lost).
// qa for the pair is 6 consecutive dwords -> merges into dwordx4+dwordx2.
// -------------------------------------------------------------------------
__global__ __launch_bounds__(256) void akfi_dual4(
    const int* __restrict__ qa,                                   // B x 3
    const int* __restrict__ o0, const int* __restrict__ s0, const int* __restrict__ l0,
    const int* __restrict__ o1, const int* __restrict__ s1, const int* __restrict__ l1,
    const int* __restrict__ op, const int* __restrict__ sp, const int* __restrict__ lp,
    int n0, int n1, int npred,
    int F, int B,
    int* __restrict__ out_idx,                                    // B x 64
    int* __restrict__ out_valid)                                  // B x 64 (0/1)
{
    long long t = (long long)blockIdx.x * blockDim.x + threadIdx.x;
    int npair = (B + 1) >> 1;
    long long total = (long long)npair * 16;
    if (t >= total) return;

    int u  = (int)(t >> 4);
    int j4 = (int)(t & 15) << 2;               // 0,4,...,60
    int q0 = u << 1;
    int q1 = q0 + 1;
    bool has1 = (q1 < B);
    const int Fm1 = F - 1;

    // Pair metadata: 6 consecutive dwords.
    const int* qp = qa + q0 * 3;
    int p0  = qp[0], a00 = qp[1], a01 = qp[2];
    int p1  = has1 ? qp[3] : 0;
    int a10 = has1 ? qp[4] : PAD_C;
    int a11 = has1 ? qp[5] : PAD_C;

    // ---- chain 0 ----
    bool c0_is0 = (a00 <= CNO_C) && (a00 != PAD_C);
    bool c0_is1 = (a01 <= CNO_C) && (a01 != PAD_C);
    bool c0_bo  = (!c0_is0) && (!c0_is1) && (p0 != PAD_C);
    const int *ord0, *st0, *ln0; int key0, nsz0; bool isc0;
    if (c0_is0)     { ord0 = o0; st0 = s0; ln0 = l0; key0 = p0 * KS_C + a00; nsz0 = n0;    isc0 = true;   }
    else if (c0_bo) { ord0 = op; st0 = sp; ln0 = lp; key0 = p0;              nsz0 = npred; isc0 = true;   }
    else            { ord0 = o1; st0 = s1; ln0 = l1; key0 = p0 * KS_C + a01; nsz0 = n1;    isc0 = c0_is1; }

    // ---- chain 1 ----
    bool c1_is0 = (a10 <= CNO_C) && (a10 != PAD_C);
    bool c1_is1 = (a11 <= CNO_C) && (a11 != PAD_C);
    bool c1_bo  = (!c1_is0) && (!c1_is1) && (p1 != PAD_C);
    const int *ord1, *st1, *ln1; int key1, nsz1; bool isc1;
    if (c1_is0)     { ord1 = o0; st1 = s0; ln1 = l0; key1 = p1 * KS_C + a10; nsz1 = n0;    isc1 = true;   }
    else if (c1_bo) { ord1 = op; st1 = sp; ln1 = lp; key1 = p1;              nsz1 = npred; isc1 = true;   }
    else            { ord1 = o1; st1 = s1; ln1 = l1; key1 = p1 * KS_C + a11; nsz1 = n1;    isc1 = c1_is1; }

    // Issue both starts/lens loads back-to-back (independent).
    int safe0 = min(max(key0, 0), nsz0 - 1);
    int safe1 = min(max(key1, 0), nsz1 - 1);
    int left0 = st0[safe0];
    int left1 = has1 ? st1[safe1] : 0;
    int cnt0  = ln0[safe0];
    int cnt1  = has1 ? ln1[safe1] : 0;
    cnt0 = min(cnt0, 64); if (!isc0) cnt0 = 0;
    cnt1 = min(cnt1, 64); if (!isc1) cnt1 = 0;

    // Issue both gathers back-to-back (independent chains).
    int i00 = left0 + j4;
    int i10 = left1 + j4;
    int g00, g01, g02, g03, g10, g11, g12, g13;
    if (i00 >= 0 && i00 + 3 <= Fm1) {
        g00 = ord0[i00]; g01 = ord0[i00 + 1]; g02 = ord0[i00 + 2]; g03 = ord0[i00 + 3];
    } else {
        g00 = ord0[min(max(i00,     0), Fm1)];
        g01 = ord0[min(max(i00 + 1, 0), Fm1)];
        g02 = ord0[min(max(i00 + 2, 0), Fm1)];
        g03 = ord0[min(max(i00 + 3, 0), Fm1)];
    }
    if (has1) {
        if (i10 >= 0 && i10 + 3 <= Fm1) {
            g10 = ord1[i10]; g11 = ord1[i10 + 1]; g12 = ord1[i10 + 2]; g13 = ord1[i10 + 3];
        } else {
            g10 = ord1[min(max(i10,     0), Fm1)];
            g11 = ord1[min(max(i10 + 1, 0), Fm1)];
            g12 = ord1[min(max(i10 + 2, 0), Fm1)];
            g13 = ord1[min(max(i10 + 3, 0), Fm1)];
        }
    } else { g10 = g11 = g12 = g13 = 0; }

    iv4 fv0 = (iv4){g00, g01, g02, g03};
    iv4 vv0 = (iv4){j4 < cnt0 ? 1 : 0, j4 + 1 < cnt0 ? 1 : 0,
                    j4 + 2 < cnt0 ? 1 : 0, j4 + 3 < cnt0 ? 1 : 0};
    long long ob0 = ((long long)q0 << 6) + j4;
    *reinterpret_cast<iv4*>(out_idx + ob0)   = fv0;
    *reinterpret_cast<iv4*>(out_valid + ob0) = vv0;

    if (has1) {
        iv4 fv1 = (iv4){g10, g11, g12, g13};
        iv4 vv1 = (iv4){j4 < cnt1 ? 1 : 0, j4 + 1 < cnt1 ? 1 : 0,
                        j4 + 2 < cnt1 ? 1 : 0, j4 + 3 < cnt1 ? 1 : 0};
        long long ob1 = ((long long)q1 << 6) + j4;
        *reinterpret_cast<iv4*>(out_idx + ob1)   = fv1;
        *reinterpret_cast<iv4*>(out_valid + ob1) = vv1;
    }
}

// -------------------------------------------------------------------------
// Generic fallbacks (mr != 64).
// -------------------------------------------------------------------------
__global__ __launch_bounds__(256) void akfi_vec4(
    const int* __restrict__ qa,
    const int* __restrict__ o0, const int* __restrict__ s0, const int* __restrict__ l0,
    const int* __restrict__ o1, const int* __restrict__ s1, const int* __restrict__ l1,
    const int* __restrict__ op, const int* __restrict__ sp, const int* __restrict__ lp,
    int n0, int n1, int npred,
    int F, int B, int mr,
    int* __restrict__ out_idx,
    int* __restrict__ out_valid)
{
    long long t = (long long)blockIdx.x * blockDim.x + threadIdx.x;
    int per_q = mr >> 2;
    long long total = (long long)B * per_q;
    if (t >= total) return;

    int q = (int)(t / per_q), j4 = (int)(t % per_q) << 2;

    int p  = qa[q * 3 + 0];
    int a0 = qa[q * 3 + 1];
    int a1 = qa[q * 3 + 2];
    bool is_c0 = (a0 <= CNO_C) && (a0 != PAD_C);
    bool is_c1 = (a1 <= CNO_C) && (a1 != PAD_C);
    bool both  = (!is_c0) && (!is_c1) && (p != PAD_C);

    const int* order; const int* starts; const int* lens;
    int key, nsz; bool isc;
    if (is_c0)      { order = o0; starts = s0; lens = l0; key = p * KS_C + a0; nsz = n0;    isc = true;  }
    else if (both)  { order = op; starts = sp; lens = lp; key = p;             nsz = npred; isc = true;  }
    else            { order = o1; starts = s1; lens = l1; key = p * KS_C + a1; nsz = n1;    isc = is_c1; }

    int safe = min(max(key, 0), nsz - 1);
    int left = starts[safe];
    int cnt  = min(lens[safe], mr);
    if (!isc) cnt = 0;
    int Fm1 = F - 1;

    int idx0 = left + j4;
    int f0, f1, f2, f3;
    if (idx0 >= 0 && idx0 + 3 <= Fm1) {
        f0 = order[idx0]; f1 = order[idx0 + 1]; f2 = order[idx0 + 2]; f3 = order[idx0 + 3];
    } else {
        f0 = order[min(max(idx0,     0), Fm1)];
        f1 = order[min(max(idx0 + 1, 0), Fm1)];
        f2 = order[min(max(idx0 + 2, 0), Fm1)];
        f3 = order[min(max(idx0 + 3, 0), Fm1)];
    }

    iv4 fv = (iv4){f0, f1, f2, f3};
    iv4 vv = (iv4){j4 < cnt ? 1 : 0, j4 + 1 < cnt ? 1 : 0,
                   j4 + 2 < cnt ? 1 : 0, j4 + 3 < cnt ? 1 : 0};
    long long ob = (long long)q * mr + j4;
    *reinterpret_cast<iv4*>(out_idx + ob)   = fv;
    *reinterpret_cast<iv4*>(out_valid + ob) = vv;
}

__global__ __launch_bounds__(256) void akfi_scalar(
    const int* __restrict__ qa,
    const int* __restrict__ o0, const int* __restrict__ s0, const int* __restrict__ l0,
    const int* __restrict__ o1, const int* __restrict__ s1, const int* __restrict__ l1,
    const int* __restrict__ op, const int* __restrict__ sp, const int* __restrict__ lp,
    int n0, int n1, int npred,
    int F, int B, int mr,
    int* __restrict__ out_idx,
    int* __restrict__ out_valid)
{
    long long t = (long long)blockIdx.x * blockDim.x + threadIdx.x;
    long long total = (long long)B * (long long)mr;
    if (t >= total) return;
    int q = (int)(t / mr), j = (int)(t % mr);

    int p  = qa[q * 3 + 0];
    int a0 = qa[q * 3 + 1];
    int a1 = qa[q * 3 + 2];
    bool is_c0 = (a0 <= CNO_C) && (a0 != PAD_C);
    bool is_c1 = (a1 <= CNO_C) && (a1 != PAD_C);
    bool both  = (!is_c0) && (!is_c1) && (p != PAD_C);

    const int* order; const int* starts; const int* lens;
    int key, nsz; bool isc;
    if (is_c0)      { order = o0; starts = s0; lens = l0; key = p * KS_C + a0; nsz = n0;    isc = true;  }
    else if (both)  { order = op; starts = sp; lens = lp; key = p;             nsz = npred; isc = true;  }
    else            { order = o1; starts = s1; lens = l1; key = p * KS_C + a1; nsz = n1;    isc = is_c1; }

    int safe = min(max(key, 0), nsz - 1);
    int left = starts[safe];
    int cnt  = min(lens[safe], mr);
    int idx  = min(max(left + j, 0), F - 1);

    long long ob = (long long)q * mr + j;
    out_idx[ob]   = order[idx];
    out_valid[ob] = (isc && j < cnt) ? 1 : 0;
}

extern "C" void kernel_launch(void* const* d_in, const int* in_sizes, int n_in,
                              void* d_out, int out_size, void* d_ws, size_t ws_size,
                              hipStream_t stream) {
    const int* qa = (const int*)d_in[0];
    const int* o0 = (const int*)d_in[1];
    const int* s0 = (const int*)d_in[2];
    const int* l0 = (const int*)d_in[3];
    const int* o1 = (const int*)d_in[4];
    const int* s1 = (const int*)d_in[5];
    const int* l1 = (const int*)d_in[6];
    const int* op = (const int*)d_in[7];
    const int* sp = (const int*)d_in[8];
    const int* lp = (const int*)d_in[9];
    int B  = in_sizes[0] / 3;
    int F  = in_sizes[1];
    int n0 = in_sizes[2];
    int n1 = in_sizes[5];
    int npred = in_sizes[8];
    int mr = out_size / (2 * B);

    int* out_idx   = (int*)d_out;
    int* out_valid = (int*)d_out + (long long)B * mr;

    int block = 256;
    if (mr == 64) {
        long long total = (long long)((B + 1) >> 1) * 16;
        int blocks = (int)((total + block - 1) / block);
        akfi_dual4<<<blocks, block, 0, stream>>>(
            qa, o0, s0, l0, o1, s1, l1, op, sp, lp,
            n0, n1, npred, F, B, out_idx, out_valid);
    } else if ((mr & 3) == 0) {
        long long total = (long long)B * (mr >> 2);
        int blocks = (int)((total + block - 1) / block);
        akfi_vec4<<<blocks, block, 0, stream>>>(
            qa, o0, s0, l0, o1, s1, l1, op, sp, lp,
            n0, n1, npred, F, B, mr, out_idx, out_valid);
    } else {
        long long total = (long long)B * (long long)mr;
        int blocks = (int)((total + block - 1) / block);
        akfi_scalar<<<blocks, block, 0, stream>>>(
            qa, o0, s0, l0, o1, s1, l1, op, sp, lp,
            n0, n1, npred, F, B, mr, out_idx, out_valid);
    }
}

// Round 8
// 31.766 us; speedup vs baseline: 1.9637x; 1.0074x over previous
//
#include <hip/hip_runtime.h>

// Problem constants (from the reference): CNO=10000, PAD=10001, KS=10003.
#define CNO_C 10000
#define PAD_C 10001
#define KS_C  10003

typedef int iv4 __attribute__((ext_vector_type(4)));

// -------------------------------------------------------------------------
// mr==64 fast path (best-known structure, R2): one thread per (query q,
// 4 consecutive offsets j4). 16 threads/query, 3.2M threads.
// Wave = 4 queries: stores are 1024B contiguous per wave instruction
// (full-line coverage), gather is 4x 256B random segments per wave.
// Falsified alternatives: LDS metadata staging (R3, -10%: lost TLP),
// vec8 per-thread widening (R6, -5%: striped stores + serial chains),
// dual-query MLP (R7, neutral: occupancy already covers latency),
// nontemporal stores (R5, -96%: 1.85x HBM write amplification).
// -------------------------------------------------------------------------
__global__ __launch_bounds__(256) void akfi_vec4_mr64(
    const int* __restrict__ qa,                                   // B x 3
    const int* __restrict__ o0, const int* __restrict__ s0, const int* __restrict__ l0,
    const int* __restrict__ o1, const int* __restrict__ s1, const int* __restrict__ l1,
    const int* __restrict__ op, const int* __restrict__ sp, const int* __restrict__ lp,
    int n0, int n1, int npred,
    int F, int B,
    int* __restrict__ out_idx,                                    // B x 64
    int* __restrict__ out_valid)                                  // B x 64 (0/1)
{
    int t = blockIdx.x * blockDim.x + threadIdx.x;
    // total = B*16 < 2^31, 32-bit arithmetic throughout
    if (t >= B * 16) return;

    int q  = t >> 4;
    int j4 = (t & 15) << 2;                    // 0,4,...,60

    int p  = qa[q * 3 + 0];
    int a0 = qa[q * 3 + 1];
    int a1 = qa[q * 3 + 2];

    bool is_c0 = (a0 <= CNO_C) && (a0 != PAD_C);
    bool is_c1 = (a1 <= CNO_C) && (a1 != PAD_C);
    bool both  = (!is_c0) && (!is_c1) && (p != PAD_C);

    // Reference select order: is_c0 -> t0; elif both_var -> pred; else t1.
    const int* order; const int* starts; const int* lens;
    int key, nsz; bool isc;
    if (is_c0)      { order = o0; starts = s0; lens = l0; key = p * KS_C + a0; nsz = n0;    isc = true;  }
    else if (both)  { order = op; starts = sp; lens = lp; key = p;             nsz = npred; isc = true;  }
    else            { order = o1; starts = s1; lens = l1; key = p * KS_C + a1; nsz = n1;    isc = is_c1; }

    int safe = min(max(key, 0), nsz - 1);
    int left = starts[safe];
    int cnt  = lens[safe];
    cnt = min(cnt, 64);
    if (!isc) cnt = 0;
    const int Fm1 = F - 1;

    int idx0 = left + j4;                      // reference clamps each to [0, F-1]
    int f0, f1, f2, f3;
    if (idx0 >= 0 && idx0 + 3 <= Fm1) {
        // contiguous, in-bounds: global_load_dwordx4
        f0 = order[idx0]; f1 = order[idx0 + 1]; f2 = order[idx0 + 2]; f3 = order[idx0 + 3];
    } else {
        f0 = order[min(max(idx0,     0), Fm1)];
        f1 = order[min(max(idx0 + 1, 0), Fm1)];
        f2 = order[min(max(idx0 + 2, 0), Fm1)];
        f3 = order[min(max(idx0 + 3, 0), Fm1)];
    }

    iv4 fv = (iv4){f0, f1, f2, f3};
    iv4 vv = (iv4){j4 < cnt ? 1 : 0, j4 + 1 < cnt ? 1 : 0,
                   j4 + 2 < cnt ? 1 : 0, j4 + 3 < cnt ? 1 : 0};

    int ob = (q << 6) + j4;                    // < 2^31, 16B-aligned
    *reinterpret_cast<iv4*>(out_idx + ob)   = fv;
    *reinterpret_cast<iv4*>(out_valid + ob) = vv;
}

// -------------------------------------------------------------------------
// Generic fallbacks (mr != 64).
// -------------------------------------------------------------------------
__global__ __launch_bounds__(256) void akfi_vec4(
    const int* __restrict__ qa,
    const int* __restrict__ o0, const int* __restrict__ s0, const int* __restrict__ l0,
    const int* __restrict__ o1, const int* __restrict__ s1, const int* __restrict__ l1,
    const int* __restrict__ op, const int* __restrict__ sp, const int* __restrict__ lp,
    int n0, int n1, int npred,
    int F, int B, int mr,
    int* __restrict__ out_idx,
    int* __restrict__ out_valid)
{
    long long t = (long long)blockIdx.x * blockDim.x + threadIdx.x;
    int per_q = mr >> 2;
    long long total = (long long)B * per_q;
    if (t >= total) return;

    int q = (int)(t / per_q), j4 = (int)(t % per_q) << 2;

    int p  = qa[q * 3 + 0];
    int a0 = qa[q * 3 + 1];
    int a1 = qa[q * 3 + 2];
    bool is_c0 = (a0 <= CNO_C) && (a0 != PAD_C);
    bool is_c1 = (a1 <= CNO_C) && (a1 != PAD_C);
    bool both  = (!is_c0) && (!is_c1) && (p != PAD_C);

    const int* order; const int* starts; const int* lens;
    int key, nsz; bool isc;
    if (is_c0)      { order = o0; starts = s0; lens = l0; key = p * KS_C + a0; nsz = n0;    isc = true;  }
    else if (both)  { order = op; starts = sp; lens = lp; key = p;             nsz = npred; isc = true;  }
    else            { order = o1; starts = s1; lens = l1; key = p * KS_C + a1; nsz = n1;    isc = is_c1; }

    int safe = min(max(key, 0), nsz - 1);
    int left = starts[safe];
    int cnt  = min(lens[safe], mr);
    if (!isc) cnt = 0;
    int Fm1 = F - 1;

    int idx0 = left + j4;
    int f0, f1, f2, f3;
    if (idx0 >= 0 && idx0 + 3 <= Fm1) {
        f0 = order[idx0]; f1 = order[idx0 + 1]; f2 = order[idx0 + 2]; f3 = order[idx0 + 3];
    } else {
        f0 = order[min(max(idx0,     0), Fm1)];
        f1 = order[min(max(idx0 + 1, 0), Fm1)];
        f2 = order[min(max(idx0 + 2, 0), Fm1)];
        f3 = order[min(max(idx0 + 3, 0), Fm1)];
    }

    iv4 fv = (iv4){f0, f1, f2, f3};
    iv4 vv = (iv4){j4 < cnt ? 1 : 0, j4 + 1 < cnt ? 1 : 0,
                   j4 + 2 < cnt ? 1 : 0, j4 + 3 < cnt ? 1 : 0};
    long long ob = (long long)q * mr + j4;
    *reinterpret_cast<iv4*>(out_idx + ob)   = fv;
    *reinterpret_cast<iv4*>(out_valid + ob) = vv;
}

__global__ __launch_bounds__(256) void akfi_scalar(
    const int* __restrict__ qa,
    const int* __restrict__ o0, const int* __restrict__ s0, const int* __restrict__ l0,
    const int* __restrict__ o1, const int* __restrict__ s1, const int* __restrict__ l1,
    const int* __restrict__ op, const int* __restrict__ sp, const int* __restrict__ lp,
    int n0, int n1, int npred,
    int F, int B, int mr,
    int* __restrict__ out_idx,
    int* __restrict__ out_valid)
{
    long long t = (long long)blockIdx.x * blockDim.x + threadIdx.x;
    long long total = (long long)B * (long long)mr;
    if (t >= total) return;
    int q = (int)(t / mr), j = (int)(t % mr);

    int p  = qa[q * 3 + 0];
    int a0 = qa[q * 3 + 1];
    int a1 = qa[q * 3 + 2];
    bool is_c0 = (a0 <= CNO_C) && (a0 != PAD_C);
    bool is_c1 = (a1 <= CNO_C) && (a1 != PAD_C);
    bool both  = (!is_c0) && (!is_c1) && (p != PAD_C);

    const int* order; const int* starts; const int* lens;
    int key, nsz; bool isc;
    if (is_c0)      { order = o0; starts = s0; lens = l0; key = p * KS_C + a0; nsz = n0;    isc = true;  }
    else if (both)  { order = op; starts = sp; lens = lp; key = p;             nsz = npred; isc = true;  }
    else            { order = o1; starts = s1; lens = l1; key = p * KS_C + a1; nsz = n1;    isc = is_c1; }

    int safe = min(max(key, 0), nsz - 1);
    int left = starts[safe];
    int cnt  = min(lens[safe], mr);
    int idx  = min(max(left + j, 0), F - 1);

    long long ob = (long long)q * mr + j;
    out_idx[ob]   = order[idx];
    out_valid[ob] = (isc && j < cnt) ? 1 : 0;
}

extern "C" void kernel_launch(void* const* d_in, const int* in_sizes, int n_in,
                              void* d_out, int out_size, void* d_ws, size_t ws_size,
                              hipStream_t stream) {
    const int* qa = (const int*)d_in[0];
    const int* o0 = (const int*)d_in[1];
    const int* s0 = (const int*)d_in[2];
    const int* l0 = (const int*)d_in[3];
    const int* o1 = (const int*)d_in[4];
    const int* s1 = (const int*)d_in[5];
    const int* l1 = (const int*)d_in[6];
    const int* op = (const int*)d_in[7];
    const int* sp = (const int*)d_in[8];
    const int* lp = (const int*)d_in[9];
    int B  = in_sizes[0] / 3;
    int F  = in_sizes[1];
    int n0 = in_sizes[2];
    int n1 = in_sizes[5];
    int npred = in_sizes[8];
    int mr = out_size / (2 * B);

    int* out_idx   = (int*)d_out;
    int* out_valid = (int*)d_out + (long long)B * mr;

    int block = 256;
    if (mr == 64) {
        int total = B * 16;
        int blocks = (total + block - 1) / block;
        akfi_vec4_mr64<<<blocks, block, 0, stream>>>(
            qa, o0, s0, l0, o1, s1, l1, op, sp, lp,
            n0, n1, npred, F, B, out_idx, out_valid);
    } else if ((mr & 3) == 0) {
        long long total = (long long)B * (mr >> 2);
        int blocks = (int)((total + block - 1) / block);
        akfi_vec4<<<blocks, block, 0, stream>>>(
            qa, o0, s0, l0, o1, s1, l1, op, sp, lp,
            n0, n1, npred, F, B, mr, out_idx, out_valid);
    } else {
        long long total = (long long)B * (long long)mr;
        int blocks = (int)((total + block - 1) / block);
        akfi_scalar<<<blocks, block, 0, stream>>>(
            qa, o0, s0, l0, o1, s1, l1, op, sp, lp,
            n0, n1, npred, F, B, mr, out_idx, out_valid);
    }
}